// Round 5
// baseline (1995.390 us; speedup 1.0000x reference)
//
// R5: 2-layer LSTM (B=256,T=512,IN=40,H=250) + linear head, persistent kernel.
// Topology: 256 wgs x 256 thr (1 wg/CU); 8 batch-groups (=XCDs) x 16
// unit-groups x 2 layers; W in LDS (bf16), B-frags in VGPRs.
//
// R5 = R4's XCD-local design with GRADED scopes (R4 hung; decouple suspects):
//  - FLAGS: __hip_atomic_load/store relaxed agent (sc1 -> LIC) — R3-proven
//    construct, propagates regardless of wg placement. Per-thread polling.
//  - H-DATA: sc0 asm ops (own-XCD L2, ~200cyc vs ~450 LIC). Correct iff
//    cliques are XCD-local (XCC_ID ticketing, learn_hip m09). Producer drains
//    sc0 h stores (vmcnt0) before barrier; tid0 sc1 flag store after barrier;
//    consumer polls LIC flag then sc0-reads same-XCD L2.
//  - BOUNDED spins (2^22 iters ~ 1e5x expected wait): protocol failure ->
//    wrong answer + finite time, never a harness hang.
// Failure decode: pass+fast = sc0+XCD works; absmax~0.5 = cliques not
// XCD-local; hang = deeper issue (revert to R3 protocol).
#include <hip/hip_runtime.h>
#include <cstdint>

#define B_TOT 256
#define T_LEN 512
#define NX    40
#define NH    250
#define HP    256          // hidden padded (dummy units produce h=0, W cols 0)
#define XP    64           // x padded
#define K0    (XP + HP)    // 320  (layer0: [x | h1_prev])
#define K1    (HP + HP)    // 512  (layer1: [h1_t | h2_prev])
#define MB    32           // batches per wg
#define NU    16           // hidden units per wg
#define NR    64           // gate rows per wg (NU*4, r = lu*4 + gate; i,f,g,o)
#define RING  8            // broadcast ring depth
#define LDSK  520          // LDS K-stride in ushorts (16B aligned; 260 dwords)
#define SPIN_CAP (1u << 22)
#define GETREG(id, off, sz) ((id) | ((off) << 6) | (((sz)-1) << 11))
#define HWREG_XCC_ID 20

typedef __attribute__((ext_vector_type(8))) short short8;
typedef __attribute__((ext_vector_type(4))) float float4v;
typedef __attribute__((ext_vector_type(4))) unsigned int uint4v;

__device__ __forceinline__ unsigned short f2bf(float f) {
  unsigned u = __float_as_uint(f);
  u += 0x7FFFu + ((u >> 16) & 1u);          // RNE
  return (unsigned short)(u >> 16);
}
__device__ __forceinline__ float bf2f(unsigned short h) {
  return __uint_as_float(((unsigned)h) << 16);
}
__device__ __forceinline__ float sigm(float x) { return 1.0f / (1.0f + __expf(-x)); }
__device__ __forceinline__ float tanh_f(float x) {
  float e = __expf(-2.0f * fabsf(x));
  float t = (1.0f - e) / (1.0f + e);
  return copysignf(t, x);
}
__device__ __forceinline__ int ld_flag(const int* p) {   // sc1 (LIC) — R3-proven
  return __hip_atomic_load(p, __ATOMIC_RELAXED, __HIP_MEMORY_SCOPE_AGENT);
}
__device__ __forceinline__ void st_flag(int* p, int v) { // sc1 (LIC) — R3-proven
  __hip_atomic_store(p, v, __ATOMIC_RELAXED, __HIP_MEMORY_SCOPE_AGENT);
}

// ---- sc0 (own-XCD L2) data ops ---------------------------------------------
// 64B load (4x dwordx4) + drain inside.
__device__ __forceinline__ void ld64_sc0(const void* p, uint4v& a, uint4v& b,
                                         uint4v& c, uint4v& d) {
  asm volatile("global_load_dwordx4 %0, %4, off sc0\n\t"
               "global_load_dwordx4 %1, %4, off offset:16 sc0\n\t"
               "global_load_dwordx4 %2, %4, off offset:32 sc0\n\t"
               "global_load_dwordx4 %3, %4, off offset:48 sc0\n\t"
               "s_waitcnt vmcnt(0)"
               : "=&v"(a), "=&v"(b), "=&v"(c), "=&v"(d)
               : "v"(p) : "memory");
}
__device__ __forceinline__ void st_dword_sc0(void* p, unsigned v) {
  asm volatile("global_store_dword %0, %1, off sc0" : : "v"(p), "v"(v) : "memory");
}
__device__ __forceinline__ void vm_drain() {
  asm volatile("s_waitcnt vmcnt(0)" ::: "memory");
}

// ---------------------------------------------------------------------------
// Per-layer persistent loop. LAYER=0: x(40->64 pad)+h1_prev, K=320.
// LAYER=1: h1_t + h2_prev, K=512; gg==0 wgs also emit y[b, t-1] (after signal).
// Flag value = completed steps by that wg. Flags 4B-strided: FL0[16],FL1[16]
// per XCD. Ring-overwrite safety: FL1>=t-7 covers h1 slot reuse; h2 slot
// reuse is implied by the data-dep check FL1>=t (monotone flags).
// ---------------------------------------------------------------------------
template <int KSTEPS, int LAYER>
__device__ __forceinline__ void run_layer(
    int tid, int gg, int b0, int u0,
    const float* __restrict__ x, float* __restrict__ out, float blinv,
    unsigned short* __restrict__ h1bc, unsigned short* __restrict__ h2bc,
    int* __restrict__ FL0, int* __restrict__ FL1, int* __restrict__ mys,
    unsigned short (*WL)[LDSK], unsigned short (*inA)[LDSK],
    float (*gbuf)[NR + 4], float* biasS, float* wlinS) {
  const int lane = tid & 63, wv = tid >> 6;
  const int quad = lane >> 4, l15 = lane & 15;
  const int Mt = wv & 1, Np = wv >> 1;   // wave -> (M-tile, N-tile-pair)

  // Preload B fragments (constant across time): B[k][n]=WL[n-row][k];
  // lane layout n = lane&15, k = quad*8 + j.
  short8 bfrag[2][KSTEPS];
#pragma unroll
  for (int ks = 0; ks < KSTEPS; ++ks) {
#pragma unroll
    for (int i = 0; i < 2; ++i)
      bfrag[i][ks] = *(const short8*)&WL[Np * 32 + i * 16 + l15][ks * 32 + quad * 8];
  }

  // cell state for (batch b0+tid>>3, units u0+2*(tid&7), +1): fp32 registers
  float cA = 0.f, cB = 0.f;

  // This thread stages bytes [tid*64, tid*64+63] of each 16KB h block:
  // LDS row tid>>3, dwords (tid&7)*16.. The two producers of those columns:
  const int pA = 2 * (tid & 7), pB = pA + 1;
  int* const fl0a = FL0 + pA;  int* const fl0b = FL0 + pB;
  int* const fl1a = FL1 + pA;  int* const fl1b = FL1 + pB;
  int* const fl1q = FL1 + (tid & 15);    // backpressure coverage (wg spans all 16)
  unsigned* const myrow = (unsigned*)&inA[tid >> 3][0];
  const size_t stgofs = (size_t)tid * 32;   // ushorts

#pragma unroll 1
  for (int t = 0; t < T_LEN; ++t) {
    // ---- per-thread poll (sc1/LIC flags) + stage into LDS (sc0/L2 data) ----
    if (LAYER == 0) {
      if (t > 0) {
        for (unsigned it = 0; it < SPIN_CAP; ++it) {
          if (ld_flag(fl0a) >= t && ld_flag(fl0b) >= t &&
              ld_flag(fl1q) >= t - (RING - 1)) break;
          __builtin_amdgcn_s_sleep(1);
        }
        uint4v v0, v1, v2, v3;
        ld64_sc0(h1bc + (size_t)((t - 1) & (RING - 1)) * B_TOT * HP +
                     (size_t)b0 * HP + stgofs, v0, v1, v2, v3);
        uint4v* q4 = (uint4v*)(myrow + 32 + (tid & 7) * 16);   // +XP ushorts
        q4[0] = v0; q4[1] = v1; q4[2] = v2; q4[3] = v3;
      }
      if (tid < 128) {   // x[b, t, 0:40] -> inA[b][0:40] (40..63 stay zero)
        int b = tid >> 2, c = tid & 3;
        const float* xp = x + ((size_t)(b0 + b) * T_LEN + (size_t)t) * NX + c * 10;
#pragma unroll
        for (int j = 0; j < 10; ++j) inA[b][c * 10 + j] = f2bf(xp[j]);
      }
    } else {
      if (t > 0) {
        for (unsigned it = 0; it < SPIN_CAP; ++it) {
          if (ld_flag(fl0a) >= t + 1 && ld_flag(fl0b) >= t + 1 &&
              ld_flag(fl1a) >= t && ld_flag(fl1b) >= t) break;
          __builtin_amdgcn_s_sleep(1);
        }
      } else {
        for (unsigned it = 0; it < SPIN_CAP; ++it) {
          if (ld_flag(fl0a) >= 1 && ld_flag(fl0b) >= 1) break;
          __builtin_amdgcn_s_sleep(1);
        }
      }
      uint4v a0, b0v, c0, d0;
      ld64_sc0(h1bc + (size_t)(t & (RING - 1)) * B_TOT * HP + (size_t)b0 * HP +
                   stgofs, a0, b0v, c0, d0);
      uint4v* q4 = (uint4v*)(myrow + (tid & 7) * 16);
      q4[0] = a0; q4[1] = b0v; q4[2] = c0; q4[3] = d0;
      if (t > 0) {
        uint4v a1, b1, c1, d1;
        ld64_sc0(h2bc + (size_t)((t - 1) & (RING - 1)) * B_TOT * HP +
                     (size_t)b0 * HP + stgofs, a1, b1, c1, d1);
        uint4v* q5 = (uint4v*)(myrow + 128 + (tid & 7) * 16);
        q5[0] = a1; q5[1] = b1; q5[2] = c1; q5[3] = d1;
      }
    }
    __syncthreads();

    // ---- gate GEMM: D[b][r] = sum_k inA[b][k] * WL[r][k] ----
    float4v acc0 = {0.f, 0.f, 0.f, 0.f};
    float4v acc1 = {0.f, 0.f, 0.f, 0.f};
#pragma unroll
    for (int ks = 0; ks < KSTEPS; ++ks) {
      short8 a = *(const short8*)&inA[Mt * 16 + l15][ks * 32 + quad * 8];
      acc0 = __builtin_amdgcn_mfma_f32_16x16x32_bf16(a, bfrag[0][ks], acc0, 0, 0, 0);
      acc1 = __builtin_amdgcn_mfma_f32_16x16x32_bf16(a, bfrag[1][ks], acc1, 0, 0, 0);
    }
    // dump C (row b = Mt*16+quad*4+reg, col r = Ntile*16 + l15)
#pragma unroll
    for (int reg = 0; reg < 4; ++reg) {
      gbuf[Mt * 16 + quad * 4 + reg][Np * 32 + l15] = acc0[reg];
      gbuf[Mt * 16 + quad * 4 + reg][Np * 32 + 16 + l15] = acc1[reg];
    }
    __syncthreads();

    // ---- gates + state update; write h (bf16, sc0 -> own-XCD L2) ----
    {
      int eb = tid >> 3, up = tid & 7;
      float4v ga = *(const float4v*)&gbuf[eb][up * 8];
      float4v gv = *(const float4v*)&gbuf[eb][up * 8 + 4];
      float iA = sigm(ga[0] + biasS[up * 8 + 0]);
      float fA = sigm(ga[1] + biasS[up * 8 + 1]);
      float gA = tanh_f(ga[2] + biasS[up * 8 + 2]);
      float oA = sigm(ga[3] + biasS[up * 8 + 3]);
      cA = fA * cA + iA * gA;
      float hA = oA * tanh_f(cA);
      float iB = sigm(gv[0] + biasS[up * 8 + 4]);
      float fB = sigm(gv[1] + biasS[up * 8 + 5]);
      float gB = tanh_f(gv[2] + biasS[up * 8 + 6]);
      float oB = sigm(gv[3] + biasS[up * 8 + 7]);
      cB = fB * cB + iB * gB;
      float hB = oB * tanh_f(cB);
      unsigned hv = (unsigned)f2bf(hA) | ((unsigned)f2bf(hB) << 16);
      unsigned* dst = (unsigned*)(LAYER ? h2bc : h1bc);
      size_t di = ((size_t)(t & (RING - 1)) * B_TOT * HP + (size_t)(b0 + eb) * HP + u0) >> 1;
      st_dword_sc0(dst + di + up, hv);
    }

    // each thread drains its sc0 h store to L2; barrier; tid0 signals via LIC.
    vm_drain();
    __syncthreads();
    if (tid == 0) st_flag(mys, t + 1);

    // ---- head: y[b, t-1] from staged h2[t-1] — AFTER signal (off crit path).
    // Reads exactly the LDS dwords this thread staged; per-thread program
    // order protects against its own next-step overwrite.
    if (LAYER == 1 && gg == 0 && t > 0) {
      int eb = tid >> 3, uc = tid & 7;
      float sum = 0.f;
#pragma unroll
      for (int j = 0; j < 4; ++j) {
        short8 hvv = *(const short8*)&inA[eb][HP + uc * 32 + j * 8];
#pragma unroll
        for (int e = 0; e < 8; ++e)
          sum += bf2f((unsigned short)hvv[e]) * wlinS[uc * 32 + j * 8 + e];
      }
      sum += __shfl_xor(sum, 1);
      sum += __shfl_xor(sum, 2);
      sum += __shfl_xor(sum, 4);
      if ((tid & 7) == 0)
        out[(size_t)(b0 + eb) * T_LEN + (t - 1)] = sigm(sum + blinv);
    }
  }

  // ---- epilogue: y[:, 511] after all L1 peers finished t=511 ----
  if (LAYER == 1 && gg == 0) {
    for (unsigned it = 0; it < SPIN_CAP; ++it) {
      if (ld_flag(fl1a) >= T_LEN && ld_flag(fl1b) >= T_LEN) break;
      __builtin_amdgcn_s_sleep(1);
    }
    {  // stage h2[511] (slot 7) into inA h2 region
      uint4v v0, v1, v2, v3;
      ld64_sc0(h2bc + (size_t)(511 & (RING - 1)) * B_TOT * HP + (size_t)b0 * HP +
                   stgofs, v0, v1, v2, v3);
      uint4v* q4 = (uint4v*)(myrow + 128 + (tid & 7) * 16);
      q4[0] = v0; q4[1] = v1; q4[2] = v2; q4[3] = v3;
    }
    __syncthreads();
    int eb = tid >> 3, uc = tid & 7;
    float sum = 0.f;
#pragma unroll
    for (int j = 0; j < 4; ++j) {
      short8 hvv = *(const short8*)&inA[eb][HP + uc * 32 + j * 8];
#pragma unroll
      for (int e = 0; e < 8; ++e)
        sum += bf2f((unsigned short)hvv[e]) * wlinS[uc * 32 + j * 8 + e];
    }
    sum += __shfl_xor(sum, 1);
    sum += __shfl_xor(sum, 2);
    sum += __shfl_xor(sum, 4);
    if ((tid & 7) == 0)
      out[(size_t)(b0 + eb) * T_LEN + 511] = sigm(sum + blinv);
  }
}

// ---------------------------------------------------------------------------
extern "C" __global__ void __launch_bounds__(256, 1) lstm_persist(
    const float* __restrict__ x,
    const float* __restrict__ Wih0, const float* __restrict__ Whh0,
    const float* __restrict__ bih0, const float* __restrict__ bhh0,
    const float* __restrict__ Wih1, const float* __restrict__ Whh1,
    const float* __restrict__ bih1, const float* __restrict__ bhh1,
    const float* __restrict__ Wlin, const float* __restrict__ blin,
    float* __restrict__ out,
    unsigned short* __restrict__ h1bc, unsigned short* __restrict__ h2bc,
    int* __restrict__ cnt) {
  __shared__ unsigned short WL[NR][LDSK];    // 66560 B  bf16 [r][k], r = lu*4+gate
  __shared__ unsigned short inA[MB][LDSK];   // 33280 B  bf16 [b][k]
  __shared__ float gbuf[MB][NR + 4];         //  8704 B  fp32 gate preacts
  __shared__ float biasS[NR];
  __shared__ float wlinS[HP];
  __shared__ int roleS;

  const int tid = threadIdx.x;

  // ---- XCD-local clique discovery: 110KB LDS forces 1 wg/CU; cooperative
  // launch => all 256 resident => exactly 32 wgs/XCD (pigeonhole). Ticket
  // within my physical XCD (s_getreg XCC_ID, m09) -> role; batch-group = XCD.
  if (tid == 0) {
    int xcd = __builtin_amdgcn_s_getreg(GETREG(HWREG_XCC_ID, 0, 4)) & 7;
    int role = __hip_atomic_fetch_add(cnt + 256 + xcd * 16, 1, __ATOMIC_RELAXED,
                                      __HIP_MEMORY_SCOPE_AGENT) & 31;
    roleS = (xcd << 8) | role;
  }
  __syncthreads();
  const int xcd = roleS >> 8;
  const int role = roleS & 255;
  const int layer = role >> 4;
  const int gg = role & 15;
  const int b0 = xcd * MB, u0 = gg * NU;

  // ---- one-time LDS fills ----
  {
    const float* Wih = layer ? Wih1 : Wih0;
    const float* Whh = layer ? Whh1 : Whh0;
    const float* bi = layer ? bih1 : bih0;
    const float* bh = layer ? bhh1 : bhh0;
    const int K = layer ? K1 : K0;
    const int xw = layer ? NH : NX;     // real width of input-part
    const int xofs = layer ? HP : XP;   // where h-part starts
    int r = tid >> 2, c = tid & 3;
    int lu = r >> 2, g = r & 3, ug = u0 + lu;
    int row = g * NH + ug;
    int kq = K >> 2;
    for (int k = c * kq; k < (c + 1) * kq; ++k) {
      float v = 0.f;
      if (ug < NH) {
        if (k < xw) v = Wih[(size_t)row * xw + k];
        else if (k >= xofs && k < xofs + NH) v = Whh[(size_t)row * NH + (k - xofs)];
      }
      WL[r][k] = f2bf(v);
    }
    if (tid < NR) {
      int lu2 = tid >> 2, g2 = tid & 3, ug2 = u0 + lu2;
      biasS[tid] = (ug2 < NH) ? (bi[g2 * NH + ug2] + bh[g2 * NH + ug2]) : 0.f;
    }
    if (tid < HP) wlinS[tid] = (tid < NH) ? Wlin[tid] : 0.f;
    for (int i = tid; i < MB * LDSK; i += 256) ((unsigned short*)inA)[i] = 0;
  }
  __syncthreads();

  float blinv = blin[0];
  // flags: 4B-strided, 32 per XCD (one 128B region per XCD)
  int* FL0 = cnt + xcd * 32;
  int* FL1 = FL0 + 16;
  int* mys = FL0 + layer * 16 + gg;

  if (layer == 0)
    run_layer<K0 / 32, 0>(tid, gg, b0, u0, x, out, blinv, h1bc, h2bc,
                          FL0, FL1, mys, WL, inA, gbuf, biasS, wlinS);
  else
    run_layer<K1 / 32, 1>(tid, gg, b0, u0, x, out, blinv, h1bc, h2bc,
                          FL0, FL1, mys, WL, inA, gbuf, biasS, wlinS);
}

extern "C" __global__ void prep_zero(int* cnt) {
  int i = blockIdx.x * 256 + threadIdx.x;
  if (i < 256 + 8 * 16)   // 256 flags + 8 tickets (64B-strided)
    __hip_atomic_store(cnt + i, 0, __ATOMIC_RELAXED, __HIP_MEMORY_SCOPE_AGENT);
}

// ---------------------------------------------------------------------------
extern "C" void kernel_launch(void* const* d_in, const int* in_sizes, int n_in,
                              void* d_out, int out_size, void* d_ws, size_t ws_size,
                              hipStream_t stream) {
  const float* x    = (const float*)d_in[0];
  const float* Wih0 = (const float*)d_in[1];
  const float* Whh0 = (const float*)d_in[2];
  const float* bih0 = (const float*)d_in[3];
  const float* bhh0 = (const float*)d_in[4];
  const float* Wih1 = (const float*)d_in[5];
  const float* Whh1 = (const float*)d_in[6];
  const float* bih1 = (const float*)d_in[7];
  const float* bih1b = (const float*)d_in[8];
  const float* Wlin = (const float*)d_in[9];
  const float* blin = (const float*)d_in[10];
  float* out = (float*)d_out;

  // workspace carve: h1bc 1MB | h2bc 1MB | flags+tickets
  unsigned short* h1bc = (unsigned short*)d_ws;
  unsigned short* h2bc = h1bc + (size_t)RING * B_TOT * HP;
  int* cnt = (int*)((char*)d_ws + 2u * (size_t)RING * B_TOT * HP * sizeof(unsigned short));

  hipLaunchKernelGGL(prep_zero, dim3(2), dim3(256), 0, stream, cnt);

  void* args[] = {&x, &Wih0, &Whh0, &bih0, &bhh0, &Wih1, &Whh1, &bih1, &bih1b,
                  &Wlin, &blin, &out, &h1bc, &h2bc, &cnt};
  hipLaunchCooperativeKernel((void*)lstm_persist, dim3(256), dim3(256), args, 0u, stream);
}

// Round 6
// 1590.178 us; speedup vs baseline: 1.2548x; 1.2548x over previous
//
// R6: 2-layer LSTM (B=256,T=512,IN=40,H=250) + linear head, persistent kernel.
// Topology: 256 wgs x 256 thr (1 wg/CU); batch-group = physical XCD (XCC_ID
// ticketing, proven R5: FETCH 646->25.7 MB); 16 unit-groups x 2 layers per
// XCD; W in LDS (bf16), B-frags in VGPRs; h data via sc0 (own-XCD L2).
//
// R6 change vs R5 (ONE variable): flag PACKING + single-load polling.
// R5 polled 3-4 flags with SEQUENTIAL dependent LIC loads (~1900 cyc/iter ->
// ~1 us/step of poll quantization; dur regressed 1478->1995 despite perfect
// data locality). Now: per XCD, 8 slots of 16B = [L0[2i],L0[2i+1],L1[2i],
// L1[2i+1]]; thread i=tid&7 loads its slot with TWO independent 8B relaxed
// agent atomic loads (co-issued, one drain) + 4 compares => ~550 cyc/iter.
// Exact per-producer min-gating (sound); ring backpressure covered by pairs
// spanning all 16 + the staging barrier. Everything else identical to R5.
#include <hip/hip_runtime.h>
#include <cstdint>

#define B_TOT 256
#define T_LEN 512
#define NX    40
#define NH    250
#define HP    256          // hidden padded (dummy units produce h=0, W cols 0)
#define XP    64           // x padded
#define K0    (XP + HP)    // 320  (layer0: [x | h1_prev])
#define K1    (HP + HP)    // 512  (layer1: [h1_t | h2_prev])
#define MB    32           // batches per wg
#define NU    16           // hidden units per wg
#define NR    64           // gate rows per wg (NU*4, r = lu*4 + gate; i,f,g,o)
#define RING  8            // broadcast ring depth
#define LDSK  520          // LDS K-stride in ushorts (16B aligned; 260 dwords)
#define SPIN_CAP (1u << 22)
#define GETREG(id, off, sz) ((id) | ((off) << 6) | (((sz)-1) << 11))
#define HWREG_XCC_ID 20

typedef __attribute__((ext_vector_type(8))) short short8;
typedef __attribute__((ext_vector_type(4))) float float4v;
typedef __attribute__((ext_vector_type(4))) unsigned int uint4v;

__device__ __forceinline__ unsigned short f2bf(float f) {
  unsigned u = __float_as_uint(f);
  u += 0x7FFFu + ((u >> 16) & 1u);          // RNE
  return (unsigned short)(u >> 16);
}
__device__ __forceinline__ float bf2f(unsigned short h) {
  return __uint_as_float(((unsigned)h) << 16);
}
__device__ __forceinline__ float sigm(float x) { return 1.0f / (1.0f + __expf(-x)); }
__device__ __forceinline__ float tanh_f(float x) {
  float e = __expf(-2.0f * fabsf(x));
  float t = (1.0f - e) / (1.0f + e);
  return copysignf(t, x);
}
__device__ __forceinline__ void st_flag(int* p, int v) { // sc1 (LIC) — proven
  __hip_atomic_store(p, v, __ATOMIC_RELAXED, __HIP_MEMORY_SCOPE_AGENT);
}
// Load one 16B flag slot as two independent 8B agent atomic loads (co-issued,
// single drain before use) -> [a,b,c,d] = [L0 2i, L0 2i+1, L1 2i, L1 2i+1].
__device__ __forceinline__ void poll_slot(const int* slot, int& a, int& b,
                                          int& c, int& d) {
  const unsigned long long* p = (const unsigned long long*)slot;
  unsigned long long q0 =
      __hip_atomic_load(p, __ATOMIC_RELAXED, __HIP_MEMORY_SCOPE_AGENT);
  unsigned long long q1 =
      __hip_atomic_load(p + 1, __ATOMIC_RELAXED, __HIP_MEMORY_SCOPE_AGENT);
  a = (int)(unsigned)(q0 & 0xFFFFFFFFull);
  b = (int)(unsigned)(q0 >> 32);
  c = (int)(unsigned)(q1 & 0xFFFFFFFFull);
  d = (int)(unsigned)(q1 >> 32);
}

// ---- sc0 (own-XCD L2) data ops (proven R5) ---------------------------------
__device__ __forceinline__ void ld64_sc0(const void* p, uint4v& a, uint4v& b,
                                         uint4v& c, uint4v& d) {
  asm volatile("global_load_dwordx4 %0, %4, off sc0\n\t"
               "global_load_dwordx4 %1, %4, off offset:16 sc0\n\t"
               "global_load_dwordx4 %2, %4, off offset:32 sc0\n\t"
               "global_load_dwordx4 %3, %4, off offset:48 sc0\n\t"
               "s_waitcnt vmcnt(0)"
               : "=&v"(a), "=&v"(b), "=&v"(c), "=&v"(d)
               : "v"(p) : "memory");
}
__device__ __forceinline__ void st_dword_sc0(void* p, unsigned v) {
  asm volatile("global_store_dword %0, %1, off sc0" : : "v"(p), "v"(v) : "memory");
}
__device__ __forceinline__ void vm_drain() {
  asm volatile("s_waitcnt vmcnt(0)" ::: "memory");
}

// ---------------------------------------------------------------------------
// Per-layer persistent loop. LAYER=0: x(40->64 pad)+h1_prev, K=320.
// LAYER=1: h1_t + h2_prev, K=512; gg==0 wgs also emit y[b, t-1] (after signal).
// Flag value = completed steps by that wg.
// ---------------------------------------------------------------------------
template <int KSTEPS, int LAYER>
__device__ __forceinline__ void run_layer(
    int tid, int gg, int b0, int u0,
    const float* __restrict__ x, float* __restrict__ out, float blinv,
    unsigned short* __restrict__ h1bc, unsigned short* __restrict__ h2bc,
    int* __restrict__ FL, int* __restrict__ mys,
    unsigned short (*WL)[LDSK], unsigned short (*inA)[LDSK],
    float (*gbuf)[NR + 4], float* biasS, float* wlinS) {
  const int lane = tid & 63, wv = tid >> 6;
  const int quad = lane >> 4, l15 = lane & 15;
  const int Mt = wv & 1, Np = wv >> 1;   // wave -> (M-tile, N-tile-pair)

  // Preload B fragments (constant across time): B[k][n]=WL[n-row][k];
  // lane layout n = lane&15, k = quad*8 + j.
  short8 bfrag[2][KSTEPS];
#pragma unroll
  for (int ks = 0; ks < KSTEPS; ++ks) {
#pragma unroll
    for (int i = 0; i < 2; ++i)
      bfrag[i][ks] = *(const short8*)&WL[Np * 32 + i * 16 + l15][ks * 32 + quad * 8];
  }

  // cell state for (batch b0+tid>>3, units u0+2*(tid&7), +1): fp32 registers
  float cA = 0.f, cB = 0.f;

  // This thread stages bytes [tid*64..+63] of each 16KB h block (LDS row
  // tid>>3, dwords (tid&7)*16..). Its flag slot covers the two producers of
  // those unit columns for BOTH layers.
  int* const slot = FL + (tid & 7) * 4;
  unsigned* const myrow = (unsigned*)&inA[tid >> 3][0];
  const size_t stgofs = (size_t)tid * 32;   // ushorts

#pragma unroll 1
  for (int t = 0; t < T_LEN; ++t) {
    // ---- per-thread poll (one slot) + stage into LDS (sc0/L2 data) ----
    if (LAYER == 0) {
      if (t > 0) {
        int a, b, c, d;
        for (unsigned it = 0; it < SPIN_CAP; ++it) {
          poll_slot(slot, a, b, c, d);
          if (a >= t && b >= t && c >= t - (RING - 1) && d >= t - (RING - 1))
            break;
          __builtin_amdgcn_s_sleep(1);
        }
        uint4v v0, v1, v2, v3;
        ld64_sc0(h1bc + (size_t)((t - 1) & (RING - 1)) * B_TOT * HP +
                     (size_t)b0 * HP + stgofs, v0, v1, v2, v3);
        uint4v* q4 = (uint4v*)(myrow + 32 + (tid & 7) * 16);   // +XP ushorts
        q4[0] = v0; q4[1] = v1; q4[2] = v2; q4[3] = v3;
      }
      if (tid < 128) {   // x[b, t, 0:40] -> inA[b][0:40] (40..63 stay zero)
        int b = tid >> 2, c = tid & 3;
        const float* xp = x + ((size_t)(b0 + b) * T_LEN + (size_t)t) * NX + c * 10;
#pragma unroll
        for (int j = 0; j < 10; ++j) inA[b][c * 10 + j] = f2bf(xp[j]);
      }
    } else {
      {
        int a, b, c, d;
        for (unsigned it = 0; it < SPIN_CAP; ++it) {
          poll_slot(slot, a, b, c, d);
          if (a >= t + 1 && b >= t + 1 && c >= t && d >= t) break;
          __builtin_amdgcn_s_sleep(1);
        }
      }
      uint4v a0, b0v, c0, d0;
      ld64_sc0(h1bc + (size_t)(t & (RING - 1)) * B_TOT * HP + (size_t)b0 * HP +
                   stgofs, a0, b0v, c0, d0);
      uint4v* q4 = (uint4v*)(myrow + (tid & 7) * 16);
      q4[0] = a0; q4[1] = b0v; q4[2] = c0; q4[3] = d0;
      if (t > 0) {
        uint4v a1, b1, c1, d1;
        ld64_sc0(h2bc + (size_t)((t - 1) & (RING - 1)) * B_TOT * HP +
                     (size_t)b0 * HP + stgofs, a1, b1, c1, d1);
        uint4v* q5 = (uint4v*)(myrow + 128 + (tid & 7) * 16);
        q5[0] = a1; q5[1] = b1; q5[2] = c1; q5[3] = d1;
      }
    }
    __syncthreads();

    // ---- gate GEMM: D[b][r] = sum_k inA[b][k] * WL[r][k] ----
    float4v acc0 = {0.f, 0.f, 0.f, 0.f};
    float4v acc1 = {0.f, 0.f, 0.f, 0.f};
#pragma unroll
    for (int ks = 0; ks < KSTEPS; ++ks) {
      short8 a = *(const short8*)&inA[Mt * 16 + l15][ks * 32 + quad * 8];
      acc0 = __builtin_amdgcn_mfma_f32_16x16x32_bf16(a, bfrag[0][ks], acc0, 0, 0, 0);
      acc1 = __builtin_amdgcn_mfma_f32_16x16x32_bf16(a, bfrag[1][ks], acc1, 0, 0, 0);
    }
    // dump C (row b = Mt*16+quad*4+reg, col r = Ntile*16 + l15)
#pragma unroll
    for (int reg = 0; reg < 4; ++reg) {
      gbuf[Mt * 16 + quad * 4 + reg][Np * 32 + l15] = acc0[reg];
      gbuf[Mt * 16 + quad * 4 + reg][Np * 32 + 16 + l15] = acc1[reg];
    }
    __syncthreads();

    // ---- gates + state update; write h (bf16, sc0 -> own-XCD L2) ----
    {
      int eb = tid >> 3, up = tid & 7;
      float4v ga = *(const float4v*)&gbuf[eb][up * 8];
      float4v gv = *(const float4v*)&gbuf[eb][up * 8 + 4];
      float iA = sigm(ga[0] + biasS[up * 8 + 0]);
      float fA = sigm(ga[1] + biasS[up * 8 + 1]);
      float gA = tanh_f(ga[2] + biasS[up * 8 + 2]);
      float oA = sigm(ga[3] + biasS[up * 8 + 3]);
      cA = fA * cA + iA * gA;
      float hA = oA * tanh_f(cA);
      float iB = sigm(gv[0] + biasS[up * 8 + 4]);
      float fB = sigm(gv[1] + biasS[up * 8 + 5]);
      float gB = tanh_f(gv[2] + biasS[up * 8 + 6]);
      float oB = sigm(gv[3] + biasS[up * 8 + 7]);
      cB = fB * cB + iB * gB;
      float hB = oB * tanh_f(cB);
      unsigned hv = (unsigned)f2bf(hA) | ((unsigned)f2bf(hB) << 16);
      unsigned* dst = (unsigned*)(LAYER ? h2bc : h1bc);
      size_t di = ((size_t)(t & (RING - 1)) * B_TOT * HP + (size_t)(b0 + eb) * HP + u0) >> 1;
      st_dword_sc0(dst + di + up, hv);
    }

    // each thread drains its sc0 h store to L2; barrier; tid0 signals via LIC.
    vm_drain();
    __syncthreads();
    if (tid == 0) st_flag(mys, t + 1);

    // ---- head: y[b, t-1] from staged h2[t-1] — AFTER signal (off crit path).
    // Reads exactly the LDS dwords this thread staged; per-thread program
    // order protects against its own next-step overwrite.
    if (LAYER == 1 && gg == 0 && t > 0) {
      int eb = tid >> 3, uc = tid & 7;
      float sum = 0.f;
#pragma unroll
      for (int j = 0; j < 4; ++j) {
        short8 hvv = *(const short8*)&inA[eb][HP + uc * 32 + j * 8];
#pragma unroll
        for (int e = 0; e < 8; ++e)
          sum += bf2f((unsigned short)hvv[e]) * wlinS[uc * 32 + j * 8 + e];
      }
      sum += __shfl_xor(sum, 1);
      sum += __shfl_xor(sum, 2);
      sum += __shfl_xor(sum, 4);
      if ((tid & 7) == 0)
        out[(size_t)(b0 + eb) * T_LEN + (t - 1)] = sigm(sum + blinv);
    }
  }

  // ---- epilogue: y[:, 511] after all L1 peers finished t=511 ----
  if (LAYER == 1 && gg == 0) {
    {
      int a, b, c, d;
      for (unsigned it = 0; it < SPIN_CAP; ++it) {
        poll_slot(slot, a, b, c, d);
        if (c >= T_LEN && d >= T_LEN) break;
        __builtin_amdgcn_s_sleep(1);
      }
    }
    {  // stage h2[511] (slot 7) into inA h2 region
      uint4v v0, v1, v2, v3;
      ld64_sc0(h2bc + (size_t)(511 & (RING - 1)) * B_TOT * HP + (size_t)b0 * HP +
                   stgofs, v0, v1, v2, v3);
      uint4v* q4 = (uint4v*)(myrow + 128 + (tid & 7) * 16);
      q4[0] = v0; q4[1] = v1; q4[2] = v2; q4[3] = v3;
    }
    __syncthreads();
    int eb = tid >> 3, uc = tid & 7;
    float sum = 0.f;
#pragma unroll
    for (int j = 0; j < 4; ++j) {
      short8 hvv = *(const short8*)&inA[eb][HP + uc * 32 + j * 8];
#pragma unroll
      for (int e = 0; e < 8; ++e)
        sum += bf2f((unsigned short)hvv[e]) * wlinS[uc * 32 + j * 8 + e];
    }
    sum += __shfl_xor(sum, 1);
    sum += __shfl_xor(sum, 2);
    sum += __shfl_xor(sum, 4);
    if ((tid & 7) == 0)
      out[(size_t)(b0 + eb) * T_LEN + 511] = sigm(sum + blinv);
  }
}

// ---------------------------------------------------------------------------
extern "C" __global__ void __launch_bounds__(256, 1) lstm_persist(
    const float* __restrict__ x,
    const float* __restrict__ Wih0, const float* __restrict__ Whh0,
    const float* __restrict__ bih0, const float* __restrict__ bhh0,
    const float* __restrict__ Wih1, const float* __restrict__ Whh1,
    const float* __restrict__ bih1, const float* __restrict__ bhh1,
    const float* __restrict__ Wlin, const float* __restrict__ blin,
    float* __restrict__ out,
    unsigned short* __restrict__ h1bc, unsigned short* __restrict__ h2bc,
    int* __restrict__ cnt) {
  __shared__ unsigned short WL[NR][LDSK];    // 66560 B  bf16 [r][k], r = lu*4+gate
  __shared__ unsigned short inA[MB][LDSK];   // 33280 B  bf16 [b][k]
  __shared__ float gbuf[MB][NR + 4];         //  8704 B  fp32 gate preacts
  __shared__ float biasS[NR];
  __shared__ float wlinS[HP];
  __shared__ int roleS;

  const int tid = threadIdx.x;

  // ---- XCD-local clique discovery (proven R5): 110KB LDS forces 1 wg/CU;
  // cooperative launch => 32 wgs/XCD. Ticket within physical XCD -> role.
  if (tid == 0) {
    int xcd = __builtin_amdgcn_s_getreg(GETREG(HWREG_XCC_ID, 0, 4)) & 7;
    int role = __hip_atomic_fetch_add(cnt + 256 + xcd * 16, 1, __ATOMIC_RELAXED,
                                      __HIP_MEMORY_SCOPE_AGENT) & 31;
    roleS = (xcd << 8) | role;
  }
  __syncthreads();
  const int xcd = roleS >> 8;
  const int role = roleS & 255;
  const int layer = role >> 4;
  const int gg = role & 15;
  const int b0 = xcd * MB, u0 = gg * NU;

  // ---- one-time LDS fills ----
  {
    const float* Wih = layer ? Wih1 : Wih0;
    const float* Whh = layer ? Whh1 : Whh0;
    const float* bi = layer ? bih1 : bih0;
    const float* bh = layer ? bhh1 : bhh0;
    const int K = layer ? K1 : K0;
    const int xw = layer ? NH : NX;     // real width of input-part
    const int xofs = layer ? HP : XP;   // where h-part starts
    int r = tid >> 2, c = tid & 3;
    int lu = r >> 2, g = r & 3, ug = u0 + lu;
    int row = g * NH + ug;
    int kq = K >> 2;
    for (int k = c * kq; k < (c + 1) * kq; ++k) {
      float v = 0.f;
      if (ug < NH) {
        if (k < xw) v = Wih[(size_t)row * xw + k];
        else if (k >= xofs && k < xofs + NH) v = Whh[(size_t)row * NH + (k - xofs)];
      }
      WL[r][k] = f2bf(v);
    }
    if (tid < NR) {
      int lu2 = tid >> 2, g2 = tid & 3, ug2 = u0 + lu2;
      biasS[tid] = (ug2 < NH) ? (bi[g2 * NH + ug2] + bh[g2 * NH + ug2]) : 0.f;
    }
    if (tid < HP) wlinS[tid] = (tid < NH) ? Wlin[tid] : 0.f;
    for (int i = tid; i < MB * LDSK; i += 256) ((unsigned short*)inA)[i] = 0;
  }
  __syncthreads();

  float blinv = blin[0];
  // flags: per XCD, 8 slots x 16B = [L0 2i, L0 2i+1, L1 2i, L1 2i+1]
  int* FL = cnt + xcd * 32;
  int* mys = FL + (gg >> 1) * 4 + layer * 2 + (gg & 1);

  if (layer == 0)
    run_layer<K0 / 32, 0>(tid, gg, b0, u0, x, out, blinv, h1bc, h2bc,
                          FL, mys, WL, inA, gbuf, biasS, wlinS);
  else
    run_layer<K1 / 32, 1>(tid, gg, b0, u0, x, out, blinv, h1bc, h2bc,
                          FL, mys, WL, inA, gbuf, biasS, wlinS);
}

extern "C" __global__ void prep_zero(int* cnt) {
  int i = blockIdx.x * 256 + threadIdx.x;
  if (i < 256 + 8 * 16)   // 256 flag ints + 8 tickets (64B-strided)
    __hip_atomic_store(cnt + i, 0, __ATOMIC_RELAXED, __HIP_MEMORY_SCOPE_AGENT);
}

// ---------------------------------------------------------------------------
extern "C" void kernel_launch(void* const* d_in, const int* in_sizes, int n_in,
                              void* d_out, int out_size, void* d_ws, size_t ws_size,
                              hipStream_t stream) {
  const float* x    = (const float*)d_in[0];
  const float* Wih0 = (const float*)d_in[1];
  const float* Whh0 = (const float*)d_in[2];
  const float* bih0 = (const float*)d_in[3];
  const float* bhh0 = (const float*)d_in[4];
  const float* Wih1 = (const float*)d_in[5];
  const float* Whh1 = (const float*)d_in[6];
  const float* bih1 = (const float*)d_in[7];
  const float* bhh1 = (const float*)d_in[8];
  const float* Wlin = (const float*)d_in[9];
  const float* blin = (const float*)d_in[10];
  float* out = (float*)d_out;

  // workspace carve: h1bc 2MB | h2bc 2MB | flags+tickets
  unsigned short* h1bc = (unsigned short*)d_ws;
  unsigned short* h2bc = h1bc + (size_t)RING * B_TOT * HP;
  int* cnt = (int*)((char*)d_ws + 2u * (size_t)RING * B_TOT * HP * sizeof(unsigned short));

  hipLaunchKernelGGL(prep_zero, dim3(2), dim3(256), 0, stream, cnt);

  void* args[] = {&x, &Wih0, &Whh0, &bih0, &bhh0, &Wih1, &Whh1, &bih1, &bhh1,
                  &Wlin, &blin, &out, &h1bc, &h2bc, &cnt};
  hipLaunchCooperativeKernel((void*)lstm_persist, dim3(256), dim3(256), args, 0u, stream);
}

// Round 8
// 1511.034 us; speedup vs baseline: 1.3205x; 1.0524x over previous
//
// R8: 2-layer LSTM (B=256,T=512,IN=40,H=250) + linear head, persistent kernel.
// Topology: 256 wgs x 256 thr (1 wg/CU); batch-group = physical XCD (XCC_ID
// ticketing, proven R5); 16 unit-groups x 2 layers per XCD; W in LDS (bf16),
// B-frags in VGPRs; h data via sc0 (own-XCD L2, proven R5/R6).
//
// R8 change vs R7 (ONE variable): flag scope sc0 -> sc1 HIP atomics.
// Evidence A/B/A: R4 (sc0 flags) HUNG, R5/R6 (sc1 flags + sc0 data) passed,
// R7 (sc0 flags) HUNG. sc0 polls can be served by the per-CU L1, which nothing
// invalidates on a persistently-hot flag line -> flags frozen -> every step's
// bounded spin runs to cap -> timeout. (sc0 works for the h rings only because
// ring slots cycle through L1 every ~8 steps; never true for spin-flags.)
// Kept from R7: packed per-XCD flags (32x4B = 2 lines), wave0 lanes 0..31
// coalesced poll (one flag/lane, ~2 transactions/wave-poll vs R6's 2048
// pollers x 2 scalar loads), per-lane bounded spins (R5/R6-proven pattern;
// __all dropped as an untested variable), x staging hoisted off detect path.
#include <hip/hip_runtime.h>
#include <cstdint>

#define B_TOT 256
#define T_LEN 512
#define NX    40
#define NH    250
#define HP    256          // hidden padded (dummy units produce h=0, W cols 0)
#define XP    64           // x padded
#define K0    (XP + HP)    // 320  (layer0: [x | h1_prev])
#define K1    (HP + HP)    // 512  (layer1: [h1_t | h2_prev])
#define MB    32           // batches per wg
#define NU    16           // hidden units per wg
#define NR    64           // gate rows per wg (NU*4, r = lu*4 + gate; i,f,g,o)
#define RING  8            // broadcast ring depth
#define LDSK  520          // LDS K-stride in ushorts (16B aligned; 260 dwords)
#define SPIN_CAP (1u << 22)
#define GETREG(id, off, sz) ((id) | ((off) << 6) | (((sz)-1) << 11))
#define HWREG_XCC_ID 20

typedef __attribute__((ext_vector_type(8))) short short8;
typedef __attribute__((ext_vector_type(4))) float float4v;
typedef __attribute__((ext_vector_type(4))) unsigned int uint4v;

__device__ __forceinline__ unsigned short f2bf(float f) {
  unsigned u = __float_as_uint(f);
  u += 0x7FFFu + ((u >> 16) & 1u);          // RNE
  return (unsigned short)(u >> 16);
}
__device__ __forceinline__ float bf2f(unsigned short h) {
  return __uint_as_float(((unsigned)h) << 16);
}
__device__ __forceinline__ float sigm(float x) { return 1.0f / (1.0f + __expf(-x)); }
__device__ __forceinline__ float tanh_f(float x) {
  float e = __expf(-2.0f * fabsf(x));
  float t = (1.0f - e) / (1.0f + e);
  return copysignf(t, x);
}
// ---- flags: sc1 HIP atomics (LIC) — visibility proven R3/R5/R6 -------------
__device__ __forceinline__ int ld_flag(const int* p) {
  return __hip_atomic_load(p, __ATOMIC_RELAXED, __HIP_MEMORY_SCOPE_AGENT);
}
__device__ __forceinline__ void st_flag(int* p, int v) {
  __hip_atomic_store(p, v, __ATOMIC_RELAXED, __HIP_MEMORY_SCOPE_AGENT);
}

// ---- sc0 (own-XCD L2) data ops — proven R5/R6 ------------------------------
__device__ __forceinline__ void ld64_sc0(const void* p, uint4v& a, uint4v& b,
                                         uint4v& c, uint4v& d) {
  asm volatile("global_load_dwordx4 %0, %4, off sc0\n\t"
               "global_load_dwordx4 %1, %4, off offset:16 sc0\n\t"
               "global_load_dwordx4 %2, %4, off offset:32 sc0\n\t"
               "global_load_dwordx4 %3, %4, off offset:48 sc0\n\t"
               "s_waitcnt vmcnt(0)"
               : "=&v"(a), "=&v"(b), "=&v"(c), "=&v"(d)
               : "v"(p) : "memory");
}
__device__ __forceinline__ void st_dword_sc0(void* p, unsigned v) {
  asm volatile("global_store_dword %0, %1, off sc0" : : "v"(p), "v"(v) : "memory");
}
__device__ __forceinline__ void vm_drain() {
  asm volatile("s_waitcnt vmcnt(0)" ::: "memory");
}

// ---------------------------------------------------------------------------
// Per-layer persistent loop. LAYER=0: x(40->64 pad)+h1_prev, K=320.
// LAYER=1: h1_t + h2_prev, K=512; gg==0 wgs also emit y[b, t-1] (after signal).
// Flags: packed per XCD, FL[0..15]=L0 wgs, FL[16..31]=L1 wgs (32x4B, 2 lines;
// wave0's 32-lane poll coalesces to ~2 transactions). Flag = completed steps.
// Ring-safety (audited R7): L0@t gates FL0>=t & FL1>=t-7; L1@t gates
// FL0>=t+1 & FL1>=t.
// ---------------------------------------------------------------------------
template <int KSTEPS, int LAYER>
__device__ __forceinline__ void run_layer(
    int tid, int gg, int b0, int u0,
    const float* __restrict__ x, float* __restrict__ out, float blinv,
    unsigned short* __restrict__ h1bc, unsigned short* __restrict__ h2bc,
    int* __restrict__ FL, int* __restrict__ mys,
    unsigned short (*WL)[LDSK], unsigned short (*inA)[LDSK],
    float (*gbuf)[NR + 4], float* biasS, float* wlinS) {
  const int lane = tid & 63, wv = tid >> 6;
  const int quad = lane >> 4, l15 = lane & 15;
  const int Mt = wv & 1, Np = wv >> 1;   // wave -> (M-tile, N-tile-pair)

  // Preload B fragments (constant across time): B[k][n]=WL[n-row][k];
  // lane layout n = lane&15, k = quad*8 + j.
  short8 bfrag[2][KSTEPS];
#pragma unroll
  for (int ks = 0; ks < KSTEPS; ++ks) {
#pragma unroll
    for (int i = 0; i < 2; ++i)
      bfrag[i][ks] = *(const short8*)&WL[Np * 32 + i * 16 + l15][ks * 32 + quad * 8];
  }

  // cell state for (batch b0+tid>>3, units u0+2*(tid&7), +1): fp32 registers
  float cA = 0.f, cB = 0.f;

  // This thread stages bytes [tid*64..+63] of each 16KB h block (LDS row
  // tid>>3, dwords (tid&7)*16..).
  unsigned* const myrow = (unsigned*)&inA[tid >> 3][0];
  const size_t stgofs = (size_t)tid * 32;   // ushorts
  const int* const myflag = FL + lane;      // wave0 lanes 0..31 poll these

#pragma unroll 1
  for (int t = 0; t < T_LEN; ++t) {
    // ---- x staging first (no producer dependency; off the detect path) ----
    if (LAYER == 0 && tid < 128) {
      int b = tid >> 2, c = tid & 3;
      const float* xp = x + ((size_t)(b0 + b) * T_LEN + (size_t)t) * NX + c * 10;
#pragma unroll
      for (int j = 0; j < 10; ++j) inA[b][c * 10 + j] = f2bf(xp[j]);
    }

    // ---- wave0 lanes 0..31: coalesced poll, per-lane exit (proven pattern)
    if ((LAYER == 1 || t > 0) && wv == 0 && lane < 32) {
      int thr;
      if (LAYER == 0) thr = (lane < 16) ? t : t - (RING - 1);
      else            thr = (lane < 16) ? t + 1 : t;
      for (unsigned it = 0; it < SPIN_CAP; ++it) {
        if (ld_flag(myflag) >= thr) break;
        __builtin_amdgcn_s_sleep(1);
      }
    }
    __syncthreads();   // release wg: all producer conditions hold

    // ---- stage h into LDS (per-thread 64B, sc0 — proven R5/R6) ----
    if (LAYER == 0) {
      if (t > 0) {
        uint4v v0, v1, v2, v3;
        ld64_sc0(h1bc + (size_t)((t - 1) & (RING - 1)) * B_TOT * HP +
                     (size_t)b0 * HP + stgofs, v0, v1, v2, v3);
        uint4v* q4 = (uint4v*)(myrow + 32 + (tid & 7) * 16);   // +XP ushorts
        q4[0] = v0; q4[1] = v1; q4[2] = v2; q4[3] = v3;
      }
    } else {
      uint4v a0, b0v, c0, d0;
      ld64_sc0(h1bc + (size_t)(t & (RING - 1)) * B_TOT * HP + (size_t)b0 * HP +
                   stgofs, a0, b0v, c0, d0);
      uint4v* q4 = (uint4v*)(myrow + (tid & 7) * 16);
      q4[0] = a0; q4[1] = b0v; q4[2] = c0; q4[3] = d0;
      if (t > 0) {
        uint4v a1, b1, c1, d1;
        ld64_sc0(h2bc + (size_t)((t - 1) & (RING - 1)) * B_TOT * HP +
                     (size_t)b0 * HP + stgofs, a1, b1, c1, d1);
        uint4v* q5 = (uint4v*)(myrow + 128 + (tid & 7) * 16);
        q5[0] = a1; q5[1] = b1; q5[2] = c1; q5[3] = d1;
      }
    }
    __syncthreads();

    // ---- gate GEMM: D[b][r] = sum_k inA[b][k] * WL[r][k] ----
    float4v acc0 = {0.f, 0.f, 0.f, 0.f};
    float4v acc1 = {0.f, 0.f, 0.f, 0.f};
#pragma unroll
    for (int ks = 0; ks < KSTEPS; ++ks) {
      short8 a = *(const short8*)&inA[Mt * 16 + l15][ks * 32 + quad * 8];
      acc0 = __builtin_amdgcn_mfma_f32_16x16x32_bf16(a, bfrag[0][ks], acc0, 0, 0, 0);
      acc1 = __builtin_amdgcn_mfma_f32_16x16x32_bf16(a, bfrag[1][ks], acc1, 0, 0, 0);
    }
    // dump C (row b = Mt*16+quad*4+reg, col r = Ntile*16 + l15)
#pragma unroll
    for (int reg = 0; reg < 4; ++reg) {
      gbuf[Mt * 16 + quad * 4 + reg][Np * 32 + l15] = acc0[reg];
      gbuf[Mt * 16 + quad * 4 + reg][Np * 32 + 16 + l15] = acc1[reg];
    }
    __syncthreads();

    // ---- gates + state update; write h (bf16, sc0 -> own-XCD L2) ----
    {
      int eb = tid >> 3, up = tid & 7;
      float4v ga = *(const float4v*)&gbuf[eb][up * 8];
      float4v gv = *(const float4v*)&gbuf[eb][up * 8 + 4];
      float iA = sigm(ga[0] + biasS[up * 8 + 0]);
      float fA = sigm(ga[1] + biasS[up * 8 + 1]);
      float gA = tanh_f(ga[2] + biasS[up * 8 + 2]);
      float oA = sigm(ga[3] + biasS[up * 8 + 3]);
      cA = fA * cA + iA * gA;
      float hA = oA * tanh_f(cA);
      float iB = sigm(gv[0] + biasS[up * 8 + 4]);
      float fB = sigm(gv[1] + biasS[up * 8 + 5]);
      float gB = tanh_f(gv[2] + biasS[up * 8 + 6]);
      float oB = sigm(gv[3] + biasS[up * 8 + 7]);
      cB = fB * cB + iB * gB;
      float hB = oB * tanh_f(cB);
      unsigned hv = (unsigned)f2bf(hA) | ((unsigned)f2bf(hB) << 16);
      unsigned* dst = (unsigned*)(LAYER ? h2bc : h1bc);
      size_t di = ((size_t)(t & (RING - 1)) * B_TOT * HP + (size_t)(b0 + eb) * HP + u0) >> 1;
      st_dword_sc0(dst + di + up, hv);
    }

    // each thread drains its sc0 h store to L2; barrier; tid0 signals via LIC.
    vm_drain();
    __syncthreads();
    if (tid == 0) st_flag(mys, t + 1);

    // ---- head: y[b, t-1] from staged h2[t-1] — AFTER signal (off crit path).
    if (LAYER == 1 && gg == 0 && t > 0) {
      int eb = tid >> 3, uc = tid & 7;
      float sum = 0.f;
#pragma unroll
      for (int j = 0; j < 4; ++j) {
        short8 hvv = *(const short8*)&inA[eb][HP + uc * 32 + j * 8];
#pragma unroll
        for (int e = 0; e < 8; ++e)
          sum += bf2f((unsigned short)hvv[e]) * wlinS[uc * 32 + j * 8 + e];
      }
      sum += __shfl_xor(sum, 1);
      sum += __shfl_xor(sum, 2);
      sum += __shfl_xor(sum, 4);
      if ((tid & 7) == 0)
        out[(size_t)(b0 + eb) * T_LEN + (t - 1)] = sigm(sum + blinv);
    }
  }

  // ---- epilogue: y[:, 511] after all L1 peers finished t=511 ----
  if (LAYER == 1 && gg == 0) {
    if (wv == 0 && lane < 32) {           // lanes 16-31 duplicate 0-15; fine
      const int* fp = FL + 16 + (lane & 15);
      for (unsigned it = 0; it < SPIN_CAP; ++it) {
        if (ld_flag(fp) >= T_LEN) break;
        __builtin_amdgcn_s_sleep(1);
      }
    }
    __syncthreads();
    {  // stage h2[511] (slot 7) into inA h2 region
      uint4v v0, v1, v2, v3;
      ld64_sc0(h2bc + (size_t)(511 & (RING - 1)) * B_TOT * HP + (size_t)b0 * HP +
                   stgofs, v0, v1, v2, v3);
      uint4v* q4 = (uint4v*)(myrow + 128 + (tid & 7) * 16);
      q4[0] = v0; q4[1] = v1; q4[2] = v2; q4[3] = v3;
    }
    __syncthreads();
    int eb = tid >> 3, uc = tid & 7;
    float sum = 0.f;
#pragma unroll
    for (int j = 0; j < 4; ++j) {
      short8 hvv = *(const short8*)&inA[eb][HP + uc * 32 + j * 8];
#pragma unroll
      for (int e = 0; e < 8; ++e)
        sum += bf2f((unsigned short)hvv[e]) * wlinS[uc * 32 + j * 8 + e];
    }
    sum += __shfl_xor(sum, 1);
    sum += __shfl_xor(sum, 2);
    sum += __shfl_xor(sum, 4);
    if ((tid & 7) == 0)
      out[(size_t)(b0 + eb) * T_LEN + 511] = sigm(sum + blinv);
  }
}

// ---------------------------------------------------------------------------
extern "C" __global__ void __launch_bounds__(256, 1) lstm_persist(
    const float* __restrict__ x,
    const float* __restrict__ Wih0, const float* __restrict__ Whh0,
    const float* __restrict__ bih0, const float* __restrict__ bhh0,
    const float* __restrict__ Wih1, const float* __restrict__ Whh1,
    const float* __restrict__ bih1, const float* __restrict__ bhh1,
    const float* __restrict__ Wlin, const float* __restrict__ blin,
    float* __restrict__ out,
    unsigned short* __restrict__ h1bc, unsigned short* __restrict__ h2bc,
    int* __restrict__ cnt) {
  __shared__ unsigned short WL[NR][LDSK];    // 66560 B  bf16 [r][k], r = lu*4+gate
  __shared__ unsigned short inA[MB][LDSK];   // 33280 B  bf16 [b][k]
  __shared__ float gbuf[MB][NR + 4];         //  8704 B  fp32 gate preacts
  __shared__ float biasS[NR];
  __shared__ float wlinS[HP];
  __shared__ int roleS;

  const int tid = threadIdx.x;

  // ---- XCD-local clique discovery (proven R5): 110KB LDS forces 1 wg/CU;
  // cooperative launch => 32 wgs/XCD. Ticket within physical XCD -> role.
  if (tid == 0) {
    int xcd = __builtin_amdgcn_s_getreg(GETREG(HWREG_XCC_ID, 0, 4)) & 7;
    int role = __hip_atomic_fetch_add(cnt + 256 + xcd * 16, 1, __ATOMIC_RELAXED,
                                      __HIP_MEMORY_SCOPE_AGENT) & 31;
    roleS = (xcd << 8) | role;
  }
  __syncthreads();
  const int xcd = roleS >> 8;
  const int role = roleS & 255;
  const int layer = role >> 4;
  const int gg = role & 15;
  const int b0 = xcd * MB, u0 = gg * NU;

  // ---- one-time LDS fills ----
  {
    const float* Wih = layer ? Wih1 : Wih0;
    const float* Whh = layer ? Whh1 : Whh0;
    const float* bi = layer ? bih1 : bih0;
    const float* bh = layer ? bhh1 : bhh0;
    const int K = layer ? K1 : K0;
    const int xw = layer ? NH : NX;     // real width of input-part
    const int xofs = layer ? HP : XP;   // where h-part starts
    int r = tid >> 2, c = tid & 3;
    int lu = r >> 2, g = r & 3, ug = u0 + lu;
    int row = g * NH + ug;
    int kq = K >> 2;
    for (int k = c * kq; k < (c + 1) * kq; ++k) {
      float v = 0.f;
      if (ug < NH) {
        if (k < xw) v = Wih[(size_t)row * xw + k];
        else if (k >= xofs && k < xofs + NH) v = Whh[(size_t)row * NH + (k - xofs)];
      }
      WL[r][k] = f2bf(v);
    }
    if (tid < NR) {
      int lu2 = tid >> 2, g2 = tid & 3, ug2 = u0 + lu2;
      biasS[tid] = (ug2 < NH) ? (bi[g2 * NH + ug2] + bh[g2 * NH + ug2]) : 0.f;
    }
    if (tid < HP) wlinS[tid] = (tid < NH) ? Wlin[tid] : 0.f;
    for (int i = tid; i < MB * LDSK; i += 256) ((unsigned short*)inA)[i] = 0;
  }
  __syncthreads();

  float blinv = blin[0];
  // flags: packed per XCD, 32 ints = 128B (2 lines): [0..15]=L0, [16..31]=L1
  int* FL = cnt + xcd * 32;
  int* mys = FL + layer * 16 + gg;

  if (layer == 0)
    run_layer<K0 / 32, 0>(tid, gg, b0, u0, x, out, blinv, h1bc, h2bc,
                          FL, mys, WL, inA, gbuf, biasS, wlinS);
  else
    run_layer<K1 / 32, 1>(tid, gg, b0, u0, x, out, blinv, h1bc, h2bc,
                          FL, mys, WL, inA, gbuf, biasS, wlinS);
}

extern "C" __global__ void prep_zero(int* cnt) {
  int i = blockIdx.x * 256 + threadIdx.x;
  if (i < 256 + 8 * 16)   // 256 flag ints + 8 tickets (64B-strided)
    __hip_atomic_store(cnt + i, 0, __ATOMIC_RELAXED, __HIP_MEMORY_SCOPE_AGENT);
}

// ---------------------------------------------------------------------------
extern "C" void kernel_launch(void* const* d_in, const int* in_sizes, int n_in,
                              void* d_out, int out_size, void* d_ws, size_t ws_size,
                              hipStream_t stream) {
  const float* x    = (const float*)d_in[0];
  const float* Wih0 = (const float*)d_in[1];
  const float* Whh0 = (const float*)d_in[2];
  const float* bih0 = (const float*)d_in[3];
  const float* bhh0 = (const float*)d_in[4];
  const float* Wih1 = (const float*)d_in[5];
  const float* Whh1 = (const float*)d_in[6];
  const float* bih1 = (const float*)d_in[7];
  const float* bhh1 = (const float*)d_in[8];
  const float* Wlin = (const float*)d_in[9];
  const float* blin = (const float*)d_in[10];
  float* out = (float*)d_out;

  // workspace carve: h1bc 2MB | h2bc 2MB | flags+tickets
  unsigned short* h1bc = (unsigned short*)d_ws;
  unsigned short* h2bc = h1bc + (size_t)RING * B_TOT * HP;
  int* cnt = (int*)((char*)d_ws + 2u * (size_t)RING * B_TOT * HP * sizeof(unsigned short));

  hipLaunchKernelGGL(prep_zero, dim3(2), dim3(256), 0, stream, cnt);

  void* args[] = {&x, &Wih0, &Whh0, &bih0, &bhh0, &Wih1, &Whh1, &bih1, &bhh1,
                  &Wlin, &blin, &out, &h1bc, &h2bc, &cnt};
  hipLaunchCooperativeKernel((void*)lstm_persist, dim3(256), dim3(256), args, 0u, stream);
}